// Round 9
// baseline (6013.916 us; speedup 1.0000x reference)
//
#include <hip/hip_runtime.h>

// B=8, C=64, N=2048, K=32, H=8, d=8. Inputs FLOAT32 (bf16-rounded values in
// f32 storage); output FLOAT32. Full fp32 pipeline. All state in d_ws
// (~14.6 MiB). R9: knn uses xT (point-major transpose, overlaid on A1 region)
// + ds_read_b128 dot + register-hoisted A-row + lazy top-2 selection; attn
// drops Wq LDS staging (8 blocks/CU); bn_partial grid 64->256.

#define NN 2048

// ---------------------------------------------------------------- prep ------
// Per 32-point tile: xx = sum x^2; K/V projections (fp32, point-major);
// xT[point][chan] transpose for knn.
__global__ __launch_bounds__(256) void prep_kernel(
    const float* __restrict__ x, const float* __restrict__ Wk,
    const float* __restrict__ Wv, float* __restrict__ xx,
    float* __restrict__ KT, float* __restrict__ VT, float* __restrict__ xT)
{
    __shared__ float xs[64][33];
    __shared__ float wks[4096], wvs[4096];
    const int t = threadIdx.x;
    const int b = blockIdx.x >> 6;
    const int n0 = (blockIdx.x & 63) * 32;
    for (int i = 0; i < 16; ++i) {
        int e = t + 256 * i;
        wks[e] = Wk[e];
        wvs[e] = Wv[e];
    }
    for (int i = 0; i < 8; ++i) {
        int e = t + 256 * i;
        xs[e >> 5][e & 31] = x[((size_t)b * 64 + (e >> 5)) * 2048 + n0 + (e & 31)];
    }
    __syncthreads();
    if (t < 32) {
        float s = 0.f;
#pragma unroll
        for (int c = 0; c < 64; ++c) { float v = xs[c][t]; s += v * v; }
        xx[b * 2048 + n0 + t] = s;
    }
    {   // xT: 8 elems/thread -> two float4 stores
        int p = t >> 3, c0 = (t & 7) * 8;
        float* dst = xT + ((size_t)(b * 2048 + n0 + p)) * 64 + c0;
        *reinterpret_cast<float4*>(dst) =
            make_float4(xs[c0 + 0][p], xs[c0 + 1][p], xs[c0 + 2][p], xs[c0 + 3][p]);
        *reinterpret_cast<float4*>(dst + 4) =
            make_float4(xs[c0 + 4][p], xs[c0 + 5][p], xs[c0 + 6][p], xs[c0 + 7][p]);
    }
    {
        int p = t & 31, g = t >> 5;  // 8 output channels per thread
        float xv[64];
#pragma unroll
        for (int c = 0; c < 64; ++c) xv[c] = xs[c][p];
        size_t base = ((size_t)(b * 2048 + n0 + p)) * 64 + g * 8;
        float ok[8], ov[8];
#pragma unroll
        for (int oi = 0; oi < 8; ++oi) {
            int o = g * 8 + oi;
            float ak = 0.f, av = 0.f;
#pragma unroll
            for (int c = 0; c < 64; ++c) {
                float xc = xv[c];
                ak += wks[o * 64 + c] * xc;
                av += wvs[o * 64 + c] * xc;
            }
            ok[oi] = ak; ov[oi] = av;
        }
        *reinterpret_cast<float4*>(KT + base)     = make_float4(ok[0], ok[1], ok[2], ok[3]);
        *reinterpret_cast<float4*>(KT + base + 4) = make_float4(ok[4], ok[5], ok[6], ok[7]);
        *reinterpret_cast<float4*>(VT + base)     = make_float4(ov[0], ov[1], ov[2], ov[3]);
        *reinterpret_cast<float4*>(VT + base + 4) = make_float4(ov[4], ov[5], ov[6], ov[7]);
    }
}

// ----------------------------------------------------------------- knn ------
// Fused distances + top-32, all batches, 4096 blocks. Block = 4 rows (1/wave).
// xT point-major: stage 64x64 B-tile via float4+ds_write_b128; dot via
// ds_read_b128; A-row hoisted to 64 regs; lazy top-2 selection.
__global__ __launch_bounds__(256) void knn_kernel(
    const float* __restrict__ xT, const float* __restrict__ xx,
    int* __restrict__ idx)
{
    __shared__ float Bs[64][68];   // row stride 272B: 16B-aligned, perm mod 8
    __shared__ float xxs[2048];
    const int t = threadIdx.x, w = t >> 6, lane = t & 63;
    const int b = blockIdx.x >> 9;
    const int r0 = (blockIdx.x & 511) * 4;
    for (int i = 0; i < 8; ++i) { int e = t + 256 * i; xxs[e] = xx[b * 2048 + e]; }
    float xv[64];  // this wave's A-row (broadcast loads)
    {
        const float* xrow = xT + ((size_t)(b * 2048 + r0 + w)) * 64;
#pragma unroll
        for (int k = 0; k < 16; ++k) {
            float4 f = *reinterpret_cast<const float4*>(xrow + k * 4);
            xv[k * 4 + 0] = f.x; xv[k * 4 + 1] = f.y;
            xv[k * 4 + 2] = f.z; xv[k * 4 + 3] = f.w;
        }
    }
    const float xxr = xx[b * 2048 + r0 + w];
    float v[32];
#pragma unroll
    for (int jt = 0; jt < 32; ++jt) {
        __syncthreads();
#pragma unroll
        for (int i = 0; i < 4; ++i) {   // stage: 4 float4 per thread
            int e = t + 256 * i;
            int p = e >> 4, c0 = (e & 15) * 4;
            *reinterpret_cast<float4*>(&Bs[p][c0]) =
                *reinterpret_cast<const float4*>(xT + ((size_t)(b * 2048 + jt * 64 + p)) * 64 + c0);
        }
        __syncthreads();
        float acc = 0.f;
#pragma unroll
        for (int c0 = 0; c0 < 64; c0 += 4) {
            float4 bb = *reinterpret_cast<const float4*>(&Bs[lane][c0]);
            acc += xv[c0 + 0] * bb.x + xv[c0 + 1] * bb.y
                 + xv[c0 + 2] * bb.z + xv[c0 + 3] * bb.w;
        }
        v[jt] = 2.f * acc - xxr - xxs[jt * 64 + lane];
    }
    // lazy top-2 selection
    unsigned mask = 0u;
    float a1 = -INFINITY, a2 = -INFINITY;
    int i1 = -1, i2 = -1;
#pragma unroll
    for (int j = 0; j < 32; ++j) {  // strict > keeps lowest j on ties
        float val = v[j];
        if (val > a1) { a2 = a1; i2 = i1; a1 = val; i1 = j; }
        else if (val > a2) { a2 = val; i2 = j; }
    }
    int* orow = idx + ((size_t)(b * 2048 + r0 + w)) * 32;
    for (int it = 0; it < 32; ++it) {
        float bv = (i1 >= 0) ? a1 : -INFINITY;
        int bi = (i1 >= 0) ? (i1 * 64 + lane) : 0x7FFFFFFF;
#pragma unroll
        for (int d = 1; d < 64; d <<= 1) {
            float ov = __shfl_xor(bv, d);
            int oi = __shfl_xor(bi, d);
            bool take = (ov > bv) || (ov == bv && oi < bi);
            bv = take ? ov : bv;
            bi = take ? oi : bi;
        }
        if (lane == 0) orow[it] = bi;
        if (lane == (bi & 63) && i1 == (bi >> 6)) {  // owner consumes
            mask |= 1u << i1;
            a1 = a2; i1 = i2;
            a2 = -INFINITY; i2 = -1;
            if (i1 < 0) {  // cache empty -> masked rescan
#pragma unroll
                for (int j = 0; j < 32; ++j) {
                    if (!((mask >> j) & 1u)) {
                        float val = v[j];
                        if (val > a1) { a2 = a1; i2 = i1; a1 = val; i1 = j; }
                        else if (val > a2) { a2 = val; i2 = j; }
                    }
                }
            }
        }
    }
}

// ---------------------------------------------------------------- attn ------
// Per point: q = (Wq@x_n)/sqrt(8) (wave 1, straight from L2-hot Wq); gather
// 32 neighbor K/V rows; energy = q.K[nbr]; serial softmax; out = sum a*V[nbr]
// - V[n]. A1 = x + out, fp32 point-major. LDS ~20KB -> 8 blocks/CU.
__global__ __launch_bounds__(256) void attn_kernel(
    const float* __restrict__ x, const float* __restrict__ Wq,
    const float* __restrict__ KT, const float* __restrict__ VT,
    const int* __restrict__ idx, float* __restrict__ A1)
{
    __shared__ int idxs[32];
    __shared__ float xq[64];
    __shared__ float qs[64];
    __shared__ float Kn[32][66], Vn[32][66];
    __shared__ float es[256], av[256];
    const int t = threadIdx.x;
    const int b = blockIdx.x >> 11;
    const int n = blockIdx.x & 2047;
    const size_t pbase = ((size_t)(b * 2048 + n)) * 64;
    if (t < 32) idxs[t] = idx[((size_t)(b * 2048 + n)) * 32 + t] & 2047;  // clamp
    else if (t < 96) xq[t - 32] = x[((size_t)b * 64 + (t - 32)) * 2048 + n];
    __syncthreads();
    {   // gather K/V neighbor rows (all threads)
        int j = t >> 3, c0 = (t & 7) * 8;
        size_t nb = ((size_t)(b * 2048 + idxs[j])) * 64 + c0;
        float4 ka = *reinterpret_cast<const float4*>(KT + nb);
        float4 kb = *reinterpret_cast<const float4*>(KT + nb + 4);
        float4 va = *reinterpret_cast<const float4*>(VT + nb);
        float4 vb = *reinterpret_cast<const float4*>(VT + nb + 4);
        Kn[j][c0 + 0] = ka.x; Kn[j][c0 + 1] = ka.y; Kn[j][c0 + 2] = ka.z; Kn[j][c0 + 3] = ka.w;
        Kn[j][c0 + 4] = kb.x; Kn[j][c0 + 5] = kb.y; Kn[j][c0 + 6] = kb.z; Kn[j][c0 + 7] = kb.w;
        Vn[j][c0 + 0] = va.x; Vn[j][c0 + 1] = va.y; Vn[j][c0 + 2] = va.z; Vn[j][c0 + 3] = va.w;
        Vn[j][c0 + 4] = vb.x; Vn[j][c0 + 5] = vb.y; Vn[j][c0 + 6] = vb.z; Vn[j][c0 + 7] = vb.w;
    }
    if (t >= 64 && t < 128) {  // q on wave 1 (Wq L2-resident across blocks)
        int o = t - 64;
        float a = 0.f;
#pragma unroll
        for (int c = 0; c < 64; ++c) a += Wq[o * 64 + c] * xq[c];
        qs[o] = a * 0.35355339059327379f;
    }
    __syncthreads();
    {
        int h = t >> 5, j = t & 31;
        float e = 0.f;
#pragma unroll
        for (int d = 0; d < 8; ++d) e += qs[h * 8 + d] * Kn[j][h * 8 + d];
        es[h * 32 + j] = e;
    }
    __syncthreads();
    if (t < 8) {  // serial per-head softmax (denominator >= 1)
        float mx = -INFINITY;
#pragma unroll
        for (int j = 0; j < 32; ++j) mx = fmaxf(mx, es[t * 32 + j]);
        float pv[32], s = 0.f;
#pragma unroll
        for (int j = 0; j < 32; ++j) { pv[j] = __expf(es[t * 32 + j] - mx); s += pv[j]; }
        float inv = 1.f / s;
#pragma unroll
        for (int j = 0; j < 32; ++j) av[t * 32 + j] = pv[j] * inv;
    }
    __syncthreads();
    if (t < 64) {
        int h = t >> 3;
        float acc = 0.f;
#pragma unroll
        for (int j = 0; j < 32; ++j) acc += av[h * 32 + j] * Vn[j][t];
        A1[pbase + t] = acc - VT[pbase + t] + xq[t];
    }
}

// ------------------------------------------------------------- BN stats -----
// 256 blocks: b = blockIdx>>5, 64-point chunk each.
__global__ __launch_bounds__(256) void bn_partial_kernel(
    const float* __restrict__ Y, float* __restrict__ psum, float* __restrict__ psq)
{
    __shared__ float rs[4][64], rq[4][64];
    const int t = threadIdx.x;
    const int c = t & 63, pg = t >> 6;
    const int b = blockIdx.x >> 5;
    const int n0 = (blockIdx.x & 31) * 64;
    float s = 0.f, q = 0.f;
    for (int k = 0; k < 16; ++k) {
        float v = Y[((size_t)(b * 2048 + n0 + pg * 16 + k)) * 64 + c];
        s += v; q += v * v;
    }
    rs[pg][c] = s; rq[pg][c] = q;
    __syncthreads();
    if (t < 64) {
        psum[blockIdx.x * 64 + t] = rs[0][t] + rs[1][t] + rs[2][t] + rs[3][t];
        psq[blockIdx.x * 64 + t]  = rq[0][t] + rq[1][t] + rq[2][t] + rq[3][t];
    }
}

__global__ void bn_final_kernel(
    const float* __restrict__ psum, const float* __restrict__ psq,
    const float* __restrict__ gamma, const float* __restrict__ beta,
    float* __restrict__ sc, float* __restrict__ sh)
{
    int c = threadIdx.x;  // 64 threads
    float s = 0.f, q = 0.f;
    for (int i = 0; i < 256; ++i) { s += psum[i * 64 + c]; q += psq[i * 64 + c]; }
    float mean = s * (1.f / 16384.f);
    float var = q * (1.f / 16384.f) - mean * mean;
    float g = gamma[c] * rsqrtf(var + 1e-5f);
    sc[c] = g;
    sh[c] = beta[c] - mean * g;
}

// ------------------------------------------------------------ FFN fused -----
// Per 64-point tile: x1 = BN1(A1) -> h = leaky(W1@x1) (LDS) -> P2 = x1 + W2@h.
__global__ __launch_bounds__(256) void ffn_kernel(
    const float* __restrict__ A1, const float* __restrict__ W1,
    const float* __restrict__ W2, const float* __restrict__ s1,
    const float* __restrict__ t1, float* __restrict__ P2)
{
    __shared__ float W1s[8192];
    __shared__ float W2s[8192];
    __shared__ float xs[64][65];
    __shared__ float hs[64][129];
    __shared__ float sts[64], stt[64];
    const int t = threadIdx.x;
    const int b = blockIdx.x >> 5;
    const int n0 = (blockIdx.x & 31) * 64;
    if (t < 64) { sts[t] = s1[t]; stt[t] = t1[t]; }
    for (int i = 0; i < 32; ++i) {
        int e = t + 256 * i;
        W1s[e] = W1[e];
        W2s[e] = W2[e];
    }
    __syncthreads();
    for (int i = 0; i < 16; ++i) {
        int e = t + 256 * i, p = e >> 6, c = e & 63;
        xs[p][c] = A1[((size_t)(b * 2048 + n0 + p)) * 64 + c] * sts[c] + stt[c];
    }
    __syncthreads();
    const int p = t & 63, g = t >> 6;
    {   // h: 32 channels per thread
        float xv[64];
#pragma unroll
        for (int c = 0; c < 64; ++c) xv[c] = xs[p][c];
        for (int u = 0; u < 32; ++u) {
            int j = g * 32 + u;
            float acc = 0.f;
#pragma unroll
            for (int c = 0; c < 64; ++c) acc += W1s[j * 64 + c] * xv[c];
            hs[p][j] = (acc > 0.f) ? acc : 0.2f * acc;  // LeakyReLU 0.2
        }
    }
    __syncthreads();
    {   // P2: 16 channels per thread
        float hv[128];
#pragma unroll
        for (int j = 0; j < 128; ++j) hv[j] = hs[p][j];
        const size_t pbase = ((size_t)(b * 2048 + n0 + p)) * 64 + g * 16;
        float o4[16];
#pragma unroll
        for (int oi = 0; oi < 16; ++oi) {
            int o = g * 16 + oi;
            float a = xs[p][o];  // residual x1
#pragma unroll
            for (int j = 0; j < 128; ++j) a += W2s[o * 128 + j] * hv[j];
            o4[oi] = a;
        }
#pragma unroll
        for (int q = 0; q < 4; ++q)
            *reinterpret_cast<float4*>(P2 + pbase + q * 4) =
                make_float4(o4[q * 4], o4[q * 4 + 1], o4[q * 4 + 2], o4[q * 4 + 3]);
    }
}

// ---------------------------------------------------------------- final -----
// out = BN2(P2), fp32, layout (B, C, N).
__global__ __launch_bounds__(256) void final_kernel(
    const float* __restrict__ P2, const float* __restrict__ s2,
    const float* __restrict__ t2, float* __restrict__ out)
{
    __shared__ float ts[64][65];
    __shared__ float sts[64], stt[64];
    const int t = threadIdx.x;
    const int b = blockIdx.x >> 5;
    const int n0 = (blockIdx.x & 31) * 64;
    if (t < 64) { sts[t] = s2[t]; stt[t] = t2[t]; }
    __syncthreads();
    for (int i = 0; i < 16; ++i) {
        int e = t + 256 * i, p = e >> 6, c = e & 63;
        ts[p][c] = P2[((size_t)(b * 2048 + n0 + p)) * 64 + c] * sts[c] + stt[c];
    }
    __syncthreads();
    const int c = t >> 2, p0 = (t & 3) * 16;
    float* dst = out + ((size_t)(b * 64 + c)) * 2048 + n0 + p0;
#pragma unroll
    for (int q = 0; q < 4; ++q)
        *reinterpret_cast<float4*>(dst + q * 4) =
            make_float4(ts[p0 + q * 4 + 0][c], ts[p0 + q * 4 + 1][c],
                        ts[p0 + q * 4 + 2][c], ts[p0 + q * 4 + 3][c]);
}

// ------------------------------------------------------- safe fallback ------
__global__ __launch_bounds__(256) void zero_kernel(float* __restrict__ out)
{
    reinterpret_cast<float4*>(out)[blockIdx.x * 256 + threadIdx.x] =
        make_float4(0.f, 0.f, 0.f, 0.f);  // 1024*256*16B = 4 MiB
}

// ---------------------------------------------------------------- launch ----
extern "C" void kernel_launch(void* const* d_in, const int* in_sizes, int n_in,
                              void* d_out, int out_size, void* d_ws, size_t ws_size,
                              hipStream_t stream)
{
    const float* x  = (const float*)d_in[0];
    const float* Wq = (const float*)d_in[1];
    const float* Wk = (const float*)d_in[2];
    const float* Wv = (const float*)d_in[3];
    const float* W1 = (const float*)d_in[4];
    const float* W2 = (const float*)d_in[5];
    const float* g1 = (const float*)d_in[6];
    const float* b1 = (const float*)d_in[7];
    const float* g2 = (const float*)d_in[8];
    const float* b2 = (const float*)d_in[9];
    float* out = (float*)d_out;
    (void)in_sizes; (void)n_in; (void)out_size;

    char* ws = (char*)d_ws;
    const size_t off_xx  = 0;                   // 64 KiB
    const size_t off_KT  = 65536;               // 4 MiB (P2 overlays after attn)
    const size_t off_VT  = off_KT  + 4194304;   // 4 MiB
    const size_t off_idx = off_VT  + 4194304;   // 2 MiB int
    const size_t off_A1  = off_idx + 2097152;   // 4 MiB (xT overlays before attn)
    const size_t off_ps1 = off_A1  + 4194304;   // 64 KiB each (256 blocks x 64)
    const size_t off_pq1 = off_ps1 + 65536;
    const size_t off_ps2 = off_pq1 + 65536;
    const size_t off_pq2 = off_ps2 + 65536;
    const size_t off_s1  = off_pq2 + 65536;
    const size_t off_t1  = off_s1 + 256;
    const size_t off_s2  = off_t1 + 256;
    const size_t off_t2  = off_s2 + 256;
    const size_t REQ     = off_t2 + 256;        // ~14.6 MiB (< known-OK 16.1)

    if (ws_size < REQ) {  // constant per capture: safe fail
        zero_kernel<<<1024, 256, 0, stream>>>(out);
        return;
    }

    float* xx = (float*)(ws + off_xx);
    float* KT = (float*)(ws + off_KT);
    float* VT = (float*)(ws + off_VT);
    int* idx  = (int*)(ws + off_idx);
    float* A1 = (float*)(ws + off_A1);
    float* xT = A1;   // xT dead before attn writes A1
    float* P2 = KT;   // KT dead after attn
    float* ps1 = (float*)(ws + off_ps1); float* pq1 = (float*)(ws + off_pq1);
    float* ps2 = (float*)(ws + off_ps2); float* pq2 = (float*)(ws + off_pq2);
    float* s1 = (float*)(ws + off_s1); float* t1 = (float*)(ws + off_t1);
    float* s2 = (float*)(ws + off_s2); float* t2 = (float*)(ws + off_t2);

    prep_kernel<<<512, 256, 0, stream>>>(x, Wk, Wv, xx, KT, VT, xT);
    knn_kernel<<<4096, 256, 0, stream>>>(xT, xx, idx);
    attn_kernel<<<16384, 256, 0, stream>>>(x, Wq, KT, VT, idx, A1);
    bn_partial_kernel<<<256, 256, 0, stream>>>(A1, ps1, pq1);
    bn_final_kernel<<<1, 64, 0, stream>>>(ps1, pq1, g1, b1, s1, t1);
    ffn_kernel<<<256, 256, 0, stream>>>(A1, W1, W2, s1, t1, P2);
    bn_partial_kernel<<<256, 256, 0, stream>>>(P2, ps2, pq2);
    bn_final_kernel<<<1, 64, 0, stream>>>(ps2, pq2, g2, b2, s2, t2);
    final_kernel<<<256, 256, 0, stream>>>(P2, s2, t2, out);
}

// Round 12
// 1189.059 us; speedup vs baseline: 5.0577x; 5.0577x over previous
//
#include <hip/hip_runtime.h>

// B=8, C=64, N=2048, K=32, H=8, d=8. Inputs FULL-PRECISION FLOAT32; output
// FLOAT32. Full fp32 pipeline (r8's proven knn arithmetic, restructured).
// R12: knn = quadrant-split phase (16384 blocks, A-row in regs, u16 candidate
// indices) + merge phase (recompute dots over 128 candidates, global top-32).
// All state in d_ws (~14.6 MiB); no device globals; no runtime API in launch.

typedef unsigned short u16;

// ---------------------------------------------------------------- prep ------
// Per 32-point tile: xx = sum x^2; K/V projections (fp32, point-major).
__global__ __launch_bounds__(256) void prep_kernel(
    const float* __restrict__ x, const float* __restrict__ Wk,
    const float* __restrict__ Wv, float* __restrict__ xx,
    float* __restrict__ KT, float* __restrict__ VT)
{
    __shared__ float xs[64][33];
    __shared__ float wks[4096], wvs[4096];
    const int t = threadIdx.x;
    const int b = blockIdx.x >> 6;
    const int n0 = (blockIdx.x & 63) * 32;
    for (int i = 0; i < 16; ++i) {
        int e = t + 256 * i;
        wks[e] = Wk[e];
        wvs[e] = Wv[e];
    }
    for (int i = 0; i < 8; ++i) {
        int e = t + 256 * i;
        xs[e >> 5][e & 31] = x[((size_t)b * 64 + (e >> 5)) * 2048 + n0 + (e & 31)];
    }
    __syncthreads();
    if (t < 32) {
        float s = 0.f;
#pragma unroll
        for (int c = 0; c < 64; ++c) { float v = xs[c][t]; s += v * v; }
        xx[b * 2048 + n0 + t] = s;
    }
    {
        int p = t & 31, g = t >> 5;  // 8 output channels per thread
        float xv[64];
#pragma unroll
        for (int c = 0; c < 64; ++c) xv[c] = xs[c][p];
        size_t base = ((size_t)(b * 2048 + n0 + p)) * 64 + g * 8;
        float ok[8], ov[8];
#pragma unroll
        for (int oi = 0; oi < 8; ++oi) {
            int o = g * 8 + oi;
            float ak = 0.f, av = 0.f;
#pragma unroll
            for (int c = 0; c < 64; ++c) {
                float xc = xv[c];
                ak += wks[o * 64 + c] * xc;
                av += wvs[o * 64 + c] * xc;
            }
            ok[oi] = ak; ov[oi] = av;
        }
        *reinterpret_cast<float4*>(KT + base)     = make_float4(ok[0], ok[1], ok[2], ok[3]);
        *reinterpret_cast<float4*>(KT + base + 4) = make_float4(ok[4], ok[5], ok[6], ok[7]);
        *reinterpret_cast<float4*>(VT + base)     = make_float4(ov[0], ov[1], ov[2], ov[3]);
        *reinterpret_cast<float4*>(VT + base + 4) = make_float4(ov[4], ov[5], ov[6], ov[7]);
    }
}

// ------------------------------------------------------------ knn part ------
// Block = (batch, quadrant q, 4 rows; 1 row/wave). 8 tiles of 64 cols each:
// stage B-tile in LDS (r8 layout, 2-way-free banks), A-row in registers
// (wave-uniform -> scalar loads), dot chain identical to r8. Then top-32 of
// the wave's 512 values -> u16 candidate col indices.
__global__ __launch_bounds__(256) void knn_part_kernel(
    const float* __restrict__ x, const float* __restrict__ xx,
    u16* __restrict__ cand)
{
    __shared__ float Bs[64][65];
    __shared__ float xxs[512];
    const int t = threadIdx.x, w = t >> 6, lane = t & 63;
    const int blk = blockIdx.x;          // 16384
    const int b = blk >> 11;
    const int q = (blk >> 9) & 3;        // quadrant
    const int rg = blk & 511;            // row group
    const int row = rg * 4 + w;
    const int col0 = q * 512;
    for (int i = 0; i < 2; ++i) xxs[t + 256 * i] = xx[b * 2048 + col0 + t + 256 * i];
    float xv[64];  // A-row, wave-uniform loads
    for (int c = 0; c < 64; ++c) xv[c] = x[((size_t)b * 64 + c) * 2048 + row];
    const float xxr = xx[b * 2048 + row];
    float v[8];
    for (int jt = 0; jt < 8; ++jt) {
        __syncthreads();  // prev dot done
        for (int i = 0; i < 16; ++i) {   // stage 64x64 (coalesced per channel)
            int e = t + 256 * i, c = e >> 6, p = e & 63;
            Bs[p][c] = x[((size_t)b * 64 + c) * 2048 + col0 + jt * 64 + p];
        }
        __syncthreads();
        float acc = 0.f;
#pragma unroll
        for (int c = 0; c < 64; ++c) acc += xv[c] * Bs[lane][c];  // r8 chain
        v[jt] = 2.f * acc - xxr - xxs[jt * 64 + lane];            // r8 formula
    }
    unsigned mask = 0u;  // consumed bits, per lane
    u16* orow = cand + ((size_t)(b * 2048 + row)) * 128 + q * 32;
    for (int it = 0; it < 32; ++it) {
        float bv = -INFINITY; int bj = 0;
#pragma unroll
        for (int j = 0; j < 8; ++j) {
            bool ok = !((mask >> j) & 1u) && (v[j] > bv);
            bv = ok ? v[j] : bv;
            bj = ok ? j : bj;
        }
        int bi = bj * 64 + lane;  // local col in [0,512); global order preserved
#pragma unroll
        for (int d = 1; d < 64; d <<= 1) {
            float ov = __shfl_xor(bv, d);
            int oi = __shfl_xor(bi, d);
            bool take = (ov > bv) || (ov == bv && oi < bi);
            bv = take ? ov : bv;
            bi = take ? oi : bi;
        }
        if (lane == (bi & 63)) mask |= 1u << (bi >> 6);
        if (lane == 0) orow[it] = (u16)(col0 + bi);
    }
}

// ----------------------------------------------------------- knn merge ------
// Per row: 128 candidates (4 quadrants x 32, distinct cols). Recompute the
// fp32 dot (identical formula/chain), pick global top-32 with (dist, lower
// col) order -> final idx.
__global__ __launch_bounds__(256) void knn_merge_kernel(
    const float* __restrict__ x, const float* __restrict__ xx,
    const u16* __restrict__ cand, int* __restrict__ idx)
{
    const int t = threadIdx.x, w = t >> 6, lane = t & 63;
    const int row = blockIdx.x * 4 + w;  // 4096 blocks
    const int b = row >> 11, n = row & 2047;
    float xv[64];  // A-row, wave-uniform
    for (int c = 0; c < 64; ++c) xv[c] = x[((size_t)b * 64 + c) * 2048 + n];
    const float xxr = xx[b * 2048 + n];
    const u16* crow = cand + (size_t)row * 128;
    float v[2]; int g[2];
#pragma unroll
    for (int s = 0; s < 2; ++s) {
        int cd = crow[lane + 64 * s];
        float acc = 0.f;
#pragma unroll 8
        for (int c = 0; c < 64; ++c) acc += xv[c] * x[((size_t)b * 64 + c) * 2048 + cd];
        v[s] = 2.f * acc - xxr - xx[b * 2048 + cd];
        g[s] = cd;
    }
    unsigned mask = 0u;
    int* orow = idx + (size_t)row * 32;
    for (int it = 0; it < 32; ++it) {
        float bv = -INFINITY; int bi = 0x7FFFFFFF;
#pragma unroll
        for (int s = 0; s < 2; ++s) {
            bool ok = !((mask >> s) & 1u) &&
                      ((v[s] > bv) || (v[s] == bv && g[s] < bi));
            bv = ok ? v[s] : bv;
            bi = ok ? g[s] : bi;
        }
#pragma unroll
        for (int d = 1; d < 64; d <<= 1) {
            float ov = __shfl_xor(bv, d);
            int oi = __shfl_xor(bi, d);
            bool take = (ov > bv) || (ov == bv && oi < bi);
            bv = take ? ov : bv;
            bi = take ? oi : bi;
        }
#pragma unroll
        for (int s = 0; s < 2; ++s)      // cols unique -> only owner matches
            if (g[s] == bi) mask |= 1u << s;
        if (lane == 0) orow[it] = bi;
    }
}

// ---------------------------------------------------------------- attn ------
// q = (Wq@x_n)/sqrt(8) on wave 1 (Wq L2-hot); gather 32 neighbor K/V rows;
// energy = q.K[nbr]; serial softmax; out = sum a*V[nbr] - V[n]; A1 = x + out.
__global__ __launch_bounds__(256) void attn_kernel(
    const float* __restrict__ x, const float* __restrict__ Wq,
    const float* __restrict__ KT, const float* __restrict__ VT,
    const int* __restrict__ idx, float* __restrict__ A1)
{
    __shared__ int idxs[32];
    __shared__ float xq[64];
    __shared__ float qs[64];
    __shared__ float Kn[32][66], Vn[32][66];
    __shared__ float es[256], av[256];
    const int t = threadIdx.x;
    const int b = blockIdx.x >> 11;
    const int n = blockIdx.x & 2047;
    const size_t pbase = ((size_t)(b * 2048 + n)) * 64;
    if (t < 32) idxs[t] = idx[((size_t)(b * 2048 + n)) * 32 + t] & 2047;  // clamp
    else if (t < 96) xq[t - 32] = x[((size_t)b * 64 + (t - 32)) * 2048 + n];
    __syncthreads();
    {
        int j = t >> 3, c0 = (t & 7) * 8;
        size_t nb = ((size_t)(b * 2048 + idxs[j])) * 64 + c0;
        float4 ka = *reinterpret_cast<const float4*>(KT + nb);
        float4 kb = *reinterpret_cast<const float4*>(KT + nb + 4);
        float4 va = *reinterpret_cast<const float4*>(VT + nb);
        float4 vb = *reinterpret_cast<const float4*>(VT + nb + 4);
        Kn[j][c0 + 0] = ka.x; Kn[j][c0 + 1] = ka.y; Kn[j][c0 + 2] = ka.z; Kn[j][c0 + 3] = ka.w;
        Kn[j][c0 + 4] = kb.x; Kn[j][c0 + 5] = kb.y; Kn[j][c0 + 6] = kb.z; Kn[j][c0 + 7] = kb.w;
        Vn[j][c0 + 0] = va.x; Vn[j][c0 + 1] = va.y; Vn[j][c0 + 2] = va.z; Vn[j][c0 + 3] = va.w;
        Vn[j][c0 + 4] = vb.x; Vn[j][c0 + 5] = vb.y; Vn[j][c0 + 6] = vb.z; Vn[j][c0 + 7] = vb.w;
    }
    if (t >= 64 && t < 128) {
        int o = t - 64;
        float a = 0.f;
#pragma unroll
        for (int c = 0; c < 64; ++c) a += Wq[o * 64 + c] * xq[c];
        qs[o] = a * 0.35355339059327379f;
    }
    __syncthreads();
    {
        int h = t >> 5, j = t & 31;
        float e = 0.f;
#pragma unroll
        for (int d = 0; d < 8; ++d) e += qs[h * 8 + d] * Kn[j][h * 8 + d];
        es[h * 32 + j] = e;
    }
    __syncthreads();
    if (t < 8) {  // serial per-head softmax (denominator >= 1)
        float mx = -INFINITY;
#pragma unroll
        for (int j = 0; j < 32; ++j) mx = fmaxf(mx, es[t * 32 + j]);
        float pv[32], s = 0.f;
#pragma unroll
        for (int j = 0; j < 32; ++j) { pv[j] = __expf(es[t * 32 + j] - mx); s += pv[j]; }
        float inv = 1.f / s;
#pragma unroll
        for (int j = 0; j < 32; ++j) av[t * 32 + j] = pv[j] * inv;
    }
    __syncthreads();
    if (t < 64) {
        int h = t >> 3;
        float acc = 0.f;
#pragma unroll
        for (int j = 0; j < 32; ++j) acc += av[h * 32 + j] * Vn[j][t];
        A1[pbase + t] = acc - VT[pbase + t] + xq[t];
    }
}

// ------------------------------------------------------------- BN stats -----
__global__ __launch_bounds__(256) void bn_partial_kernel(
    const float* __restrict__ Y, float* __restrict__ psum, float* __restrict__ psq)
{
    __shared__ float rs[4][64], rq[4][64];
    const int t = threadIdx.x;
    const int c = t & 63, pg = t >> 6;
    const int b = blockIdx.x >> 5;
    const int n0 = (blockIdx.x & 31) * 64;
    float s = 0.f, q = 0.f;
    for (int k = 0; k < 16; ++k) {
        float v = Y[((size_t)(b * 2048 + n0 + pg * 16 + k)) * 64 + c];
        s += v; q += v * v;
    }
    rs[pg][c] = s; rq[pg][c] = q;
    __syncthreads();
    if (t < 64) {
        psum[blockIdx.x * 64 + t] = rs[0][t] + rs[1][t] + rs[2][t] + rs[3][t];
        psq[blockIdx.x * 64 + t]  = rq[0][t] + rq[1][t] + rq[2][t] + rq[3][t];
    }
}

__global__ void bn_final_kernel(
    const float* __restrict__ psum, const float* __restrict__ psq,
    const float* __restrict__ gamma, const float* __restrict__ beta,
    float* __restrict__ sc, float* __restrict__ sh)
{
    int c = threadIdx.x;  // 64 threads
    float s = 0.f, q = 0.f;
    for (int i = 0; i < 256; ++i) { s += psum[i * 64 + c]; q += psq[i * 64 + c]; }
    float mean = s * (1.f / 16384.f);
    float var = q * (1.f / 16384.f) - mean * mean;
    float g = gamma[c] * rsqrtf(var + 1e-5f);
    sc[c] = g;
    sh[c] = beta[c] - mean * g;
}

// ------------------------------------------------------------ FFN fused -----
__global__ __launch_bounds__(256) void ffn_kernel(
    const float* __restrict__ A1, const float* __restrict__ W1,
    const float* __restrict__ W2, const float* __restrict__ s1,
    const float* __restrict__ t1, float* __restrict__ P2)
{
    __shared__ float W1s[8192];
    __shared__ float W2s[8192];
    __shared__ float xs[64][65];
    __shared__ float hs[64][129];
    __shared__ float sts[64], stt[64];
    const int t = threadIdx.x;
    const int b = blockIdx.x >> 5;
    const int n0 = (blockIdx.x & 31) * 64;
    if (t < 64) { sts[t] = s1[t]; stt[t] = t1[t]; }
    for (int i = 0; i < 32; ++i) {
        int e = t + 256 * i;
        W1s[e] = W1[e];
        W2s[e] = W2[e];
    }
    __syncthreads();
    for (int i = 0; i < 16; ++i) {
        int e = t + 256 * i, p = e >> 6, c = e & 63;
        xs[p][c] = A1[((size_t)(b * 2048 + n0 + p)) * 64 + c] * sts[c] + stt[c];
    }
    __syncthreads();
    const int p = t & 63, g = t >> 6;
    {
        float xv[64];
#pragma unroll
        for (int c = 0; c < 64; ++c) xv[c] = xs[p][c];
        for (int u = 0; u < 32; ++u) {
            int j = g * 32 + u;
            float acc = 0.f;
#pragma unroll
            for (int c = 0; c < 64; ++c) acc += W1s[j * 64 + c] * xv[c];
            hs[p][j] = (acc > 0.f) ? acc : 0.2f * acc;  // LeakyReLU 0.2
        }
    }
    __syncthreads();
    {
        float hv[128];
#pragma unroll
        for (int j = 0; j < 128; ++j) hv[j] = hs[p][j];
        const size_t pbase = ((size_t)(b * 2048 + n0 + p)) * 64 + g * 16;
        float o4[16];
#pragma unroll
        for (int oi = 0; oi < 16; ++oi) {
            int o = g * 16 + oi;
            float a = xs[p][o];  // residual x1
#pragma unroll
            for (int j = 0; j < 128; ++j) a += W2s[o * 128 + j] * hv[j];
            o4[oi] = a;
        }
#pragma unroll
        for (int q = 0; q < 4; ++q)
            *reinterpret_cast<float4*>(P2 + pbase + q * 4) =
                make_float4(o4[q * 4], o4[q * 4 + 1], o4[q * 4 + 2], o4[q * 4 + 3]);
    }
}

// ---------------------------------------------------------------- final -----
__global__ __launch_bounds__(256) void final_kernel(
    const float* __restrict__ P2, const float* __restrict__ s2,
    const float* __restrict__ t2, float* __restrict__ out)
{
    __shared__ float ts[64][65];
    __shared__ float sts[64], stt[64];
    const int t = threadIdx.x;
    const int b = blockIdx.x >> 5;
    const int n0 = (blockIdx.x & 31) * 64;
    if (t < 64) { sts[t] = s2[t]; stt[t] = t2[t]; }
    __syncthreads();
    for (int i = 0; i < 16; ++i) {
        int e = t + 256 * i, p = e >> 6, c = e & 63;
        ts[p][c] = P2[((size_t)(b * 2048 + n0 + p)) * 64 + c] * sts[c] + stt[c];
    }
    __syncthreads();
    const int c = t >> 2, p0 = (t & 3) * 16;
    float* dst = out + ((size_t)(b * 64 + c)) * 2048 + n0 + p0;
#pragma unroll
    for (int q = 0; q < 4; ++q)
        *reinterpret_cast<float4*>(dst + q * 4) =
            make_float4(ts[p0 + q * 4 + 0][c], ts[p0 + q * 4 + 1][c],
                        ts[p0 + q * 4 + 2][c], ts[p0 + q * 4 + 3][c]);
}

// ------------------------------------------------------- safe fallback ------
__global__ __launch_bounds__(256) void zero_kernel(float* __restrict__ out)
{
    reinterpret_cast<float4*>(out)[blockIdx.x * 256 + threadIdx.x] =
        make_float4(0.f, 0.f, 0.f, 0.f);
}

// ---------------------------------------------------------------- launch ----
extern "C" void kernel_launch(void* const* d_in, const int* in_sizes, int n_in,
                              void* d_out, int out_size, void* d_ws, size_t ws_size,
                              hipStream_t stream)
{
    const float* x  = (const float*)d_in[0];
    const float* Wq = (const float*)d_in[1];
    const float* Wk = (const float*)d_in[2];
    const float* Wv = (const float*)d_in[3];
    const float* W1 = (const float*)d_in[4];
    const float* W2 = (const float*)d_in[5];
    const float* g1 = (const float*)d_in[6];
    const float* b1 = (const float*)d_in[7];
    const float* g2 = (const float*)d_in[8];
    const float* b2 = (const float*)d_in[9];
    float* out = (float*)d_out;
    (void)in_sizes; (void)n_in; (void)out_size;

    char* ws = (char*)d_ws;
    const size_t off_xx  = 0;                   // 64 KiB
    const size_t off_KT  = 65536;               // 4 MiB (P2 overlays after attn)
    const size_t off_VT  = off_KT  + 4194304;   // 4 MiB
    const size_t off_idx = off_VT  + 4194304;   // 2 MiB int
    const size_t off_A1  = off_idx + 2097152;   // 4 MiB (cand u16 overlays pre-attn)
    const size_t off_ps1 = off_A1  + 4194304;   // 64 KiB each
    const size_t off_pq1 = off_ps1 + 65536;
    const size_t off_ps2 = off_pq1 + 65536;
    const size_t off_pq2 = off_ps2 + 65536;
    const size_t off_s1  = off_pq2 + 65536;
    const size_t off_t1  = off_s1 + 256;
    const size_t off_s2  = off_t1 + 256;
    const size_t off_t2  = off_s2 + 256;
    const size_t REQ     = off_t2 + 256;        // ~14.6 MiB (< known-OK 16.1)

    if (ws_size < REQ) {  // constant per capture: safe fail
        zero_kernel<<<1024, 256, 0, stream>>>(out);
        return;
    }

    float* xx = (float*)(ws + off_xx);
    float* KT = (float*)(ws + off_KT);
    float* VT = (float*)(ws + off_VT);
    int* idx  = (int*)(ws + off_idx);
    float* A1 = (float*)(ws + off_A1);
    u16* cand = (u16*)(ws + off_A1);   // 16384*128*2B = 4 MiB, dead before attn
    float* P2 = KT;                    // KT dead after attn
    float* ps1 = (float*)(ws + off_ps1); float* pq1 = (float*)(ws + off_pq1);
    float* ps2 = (float*)(ws + off_ps2); float* pq2 = (float*)(ws + off_pq2);
    float* s1 = (float*)(ws + off_s1); float* t1 = (float*)(ws + off_t1);
    float* s2 = (float*)(ws + off_s2); float* t2 = (float*)(ws + off_t2);

    prep_kernel<<<512, 256, 0, stream>>>(x, Wk, Wv, xx, KT, VT);
    knn_part_kernel<<<16384, 256, 0, stream>>>(x, xx, cand);
    knn_merge_kernel<<<4096, 256, 0, stream>>>(x, xx, cand, idx);
    attn_kernel<<<16384, 256, 0, stream>>>(x, Wq, KT, VT, idx, A1);
    bn_partial_kernel<<<256, 256, 0, stream>>>(A1, ps1, pq1);
    bn_final_kernel<<<1, 64, 0, stream>>>(ps1, pq1, g1, b1, s1, t1);
    ffn_kernel<<<256, 256, 0, stream>>>(A1, W1, W2, s1, t1, P2);
    bn_partial_kernel<<<256, 256, 0, stream>>>(P2, ps2, pq2);
    bn_final_kernel<<<1, 64, 0, stream>>>(ps2, pq2, g2, b2, s2, t2);
    final_kernel<<<256, 256, 0, stream>>>(P2, s2, t2, out);
}